// Round 11
// baseline (18319.415 us; speedup 1.0000x reference)
//
#include <hip/hip_runtime.h>
#include <cmath>

// Sinkhorn distance, B=8, P1=P2=2048, dim=3, EPS=1, MAX_ITER=100, THRESH=1e-9
// Outputs (flat, in return order): cost[8], pi[8*2048*2048], D[8*2048*2048]
//
// Identities:
//  - Entire iteration in log2 domain. Coords pre-scaled by log2(e):
//      d'_ij = |x'_i - y'_j| (= log2e * true distance); duals log2-space;
//      weights log2(1/2048) = -11 exactly.
//      u'_i = -11 - log2( sum_j exp2(v'_j - d'_ij) )
//  - THRESH=1e-9 < f32 ulp => reference can only stop at a bitwise fixed
//    point; R8 measured none occurs in 100 iters => run exactly 100.
//  - r2 via dot-form: r2 = |p_j|^2 + |c_i|^2 - 2 c.p  (norms staged in LDS,
//    packed in float4.w at prep). sqrt(abs(r2)) guards cancellation.
//  - Persistent kernel; cross-wg dual exchange via 32-BIT agent-scope
//    RELAXED atomics only (plain sc1 loads/stores; 64-bit atomic loads
//    lower to RMW -> 10 GB HBM, R9). No fences ever (R6: ~24us/phase).
//  - Barrier: per-wg padded epoch word. Leader: vmcnt drain -> epoch store.
//    Wave 0 polls all 64 epochs with one coalesced load + __all. No atomic
//    RMW -> no single-line serialization.
//  - Final D/pi/cost folded into the persistent kernel after the last
//    barrier (coords already in LDS; v staged to LDS; writes are the
//    unavoidable 268 MB).

constexpr int BATCH = 8;
constexpr int P = 2048;
constexpr int MAX_ITER = 100;
constexpr int WGS_PER_BATCH = 64;            // 32 rows each
constexpr int NWG = BATCH * WGS_PER_BATCH;   // 512 blocks
constexpr int TPB = 1024;                    // 16 waves
constexpr int EPOCH_STRIDE = 16;             // ints -> 64B per wg
constexpr int NEPOCH = BATCH * WGS_PER_BATCH * EPOCH_STRIDE;  // 8192 ints

#define LOG2E 1.44269504088896340736f
#define LN2   0.69314718055994530942f

typedef __attribute__((ext_vector_type(2))) float v2f;

static __device__ __forceinline__ v2f mkv2(float a, float b) { v2f r; r.x = a; r.y = b; return r; }

// Pack pre-scaled coords + squared norm into float4; init duals; zero epochs.
__global__ __launch_bounds__(256) void sk_prep(const float* __restrict__ x,
                                               const float* __restrict__ y,
                                               float4* __restrict__ xs,
                                               float4* __restrict__ ys,
                                               float* __restrict__ u,
                                               float* __restrict__ v,
                                               int* __restrict__ ep)
{
    int idx = blockIdx.x * 256 + threadIdx.x;   // 0 .. BATCH*P-1
    u[idx] = 0.0f;     // log2-space u0 = 0
    v[idx] = -11.0f;   // log2-space v0 = log2(1/2048)
    {
        float a = LOG2E * x[3*idx], b2 = LOG2E * x[3*idx+1], c = LOG2E * x[3*idx+2];
        xs[idx] = make_float4(a, b2, c, a*a + b2*b2 + c*c);
    }
    {
        float a = LOG2E * y[3*idx], b2 = LOG2E * y[3*idx+1], c = LOG2E * y[3*idx+2];
        ys[idx] = make_float4(a, b2, c, a*a + b2*b2 + c*c);
    }
    if (idx < NEPOCH) ep[idx] = 0;              // re-zeroed every call
}

// Whole Sinkhorn loop + final output in one kernel.
// Block: 1024 thr = 16 waves = 8 row-quads x 2 j-halves; 32 output rows/wg.
__global__ __launch_bounds__(TPB, 8) void sk_loop(const float4* __restrict__ xs,
                                                  const float4* __restrict__ ys,
                                                  float* u,
                                                  float* v,
                                                  int* ep,
                                                  float4* __restrict__ outPi,
                                                  float4* __restrict__ outD,
                                                  float* __restrict__ wgsum)
{
    __shared__ v2f shx[2][P/2], shy[2][P/2], shz[2][P/2], shg[2][P/2]; // 64 KiB
    __shared__ float4 shv4[P/4];                                       // 8 KiB (final)
    __shared__ float wpart[16][4];

    const int b = blockIdx.x & 7;                   // batch (XCD-local heuristic)
    const int wg = blockIdx.x >> 3;                 // 0..63 within batch
    const int wgrow = wg << 5;                      // this wg's 32-row base
    const int w = threadIdx.x >> 6;
    const int lane = threadIdx.x & 63;
    const int quad = w & 7;                         // row-quad 0..7
    const int half = w >> 3;                        // j half-range
    const int i0 = wgrow + quad * 4;
    const int tbase = half * 512 + lane;            // v2f index into LDS / duals

    const float4* xb = xs + (size_t)b * P;
    const float4* yb = ys + (size_t)b * P;
    float* ub = u + (size_t)b * P;
    float* vb = v + (size_t)b * P;
    int* eb = ep + b * WGS_PER_BATCH * EPOCH_STRIDE;

    // Stage BOTH coordinate sides + norms into LDS once.
    {
        const int t = threadIdx.x;                  // 0..1023 == P/2 entries
        float4 a0 = xb[2*t], a1 = xb[2*t + 1];
        shx[0][t] = mkv2(a0.x, a1.x);
        shy[0][t] = mkv2(a0.y, a1.y);
        shz[0][t] = mkv2(a0.z, a1.z);
        shg[0][t] = mkv2(a0.w, a1.w);
        float4 c0 = yb[2*t], c1 = yb[2*t + 1];
        shx[1][t] = mkv2(c0.x, c1.x);
        shy[1][t] = mkv2(c0.y, c1.y);
        shz[1][t] = mkv2(c0.z, c1.z);
        shg[1][t] = mkv2(c0.w, c1.w);
    }
    __syncthreads();

    #pragma unroll 1
    for (int it = 0; it < MAX_ITER; ++it) {
        #pragma unroll 1
        for (int ph = 0; ph < 2; ++ph) {
            float* dr = ph ? ub : vb;               // duals being reduced over
            float* dw = ph ? vb : ub;               // duals being written
            const int side = 1 - ph;                // LDS coord side reduced over

            // Preload this wave's dual chunks from IF (32-bit sc1 loads only).
            v2f wraw[8];
            #pragma unroll
            for (int k = 0; k < 8; ++k) {
                const int t = tbase + (k << 6);
                wraw[k].x = __hip_atomic_load(&dr[2*t],     __ATOMIC_RELAXED, __HIP_MEMORY_SCOPE_AGENT);
                wraw[k].y = __hip_atomic_load(&dr[2*t + 1], __ATOMIC_RELAXED, __HIP_MEMORY_SCOPE_AGENT);
            }

            // Own output rows' coords + norms from LDS (array index == ph).
            float cx[4], cy[4], cz[4], gx[4];
            {
                const int e0 = i0 >> 1;             // v2f index of rows i0, i0+1
                v2f xa = shx[ph][e0], xbv = shx[ph][e0 + 1];
                v2f ya = shy[ph][e0], ybv = shy[ph][e0 + 1];
                v2f za = shz[ph][e0], zbv = shz[ph][e0 + 1];
                v2f ga = shg[ph][e0], gbv = shg[ph][e0 + 1];
                cx[0] = xa.x; cx[1] = xa.y; cx[2] = xbv.x; cx[3] = xbv.y;
                cy[0] = ya.x; cy[1] = ya.y; cy[2] = ybv.x; cy[3] = ybv.y;
                cz[0] = za.x; cz[1] = za.y; cz[2] = zbv.x; cz[3] = zbv.y;
                gx[0] = ga.x; gx[1] = ga.y; gx[2] = gbv.x; gx[3] = gbv.y;
            }

            v2f acc[4];
            #pragma unroll
            for (int r = 0; r < 4; ++r) acc[r] = mkv2(0.f, 0.f);

            const v2f* sx = shx[side];
            const v2f* sy = shy[side];
            const v2f* sz = shz[side];
            const v2f* sg = shg[side];

            #pragma unroll 4
            for (int k = 0; k < 8; ++k) {
                const int t = tbase + (k << 6);
                v2f X = sx[t];
                v2f Y = sy[t];
                v2f Z = sz[t];
                v2f G = sg[t];
                v2f W;                               // exp2 at use (pipelines vmcnt)
                W.x = __builtin_amdgcn_exp2f(wraw[k].x);
                W.y = __builtin_amdgcn_exp2f(wraw[k].y);
                #pragma unroll
                for (int r = 0; r < 4; ++r) {
                    v2f t1 = X * cx[r];              // dot: pk_mul + 2 pk_fma
                    t1 = Y * cy[r] + t1;
                    t1 = Z * cz[r] + t1;
                    v2f s1 = G + gx[r];              // pk_add
                    v2f r2 = t1 * (-2.0f) + s1;      // pk_fma (inline -2.0)
                    v2f e;                           // abs = free src modifier
                    e.x = __builtin_amdgcn_exp2f(-__builtin_amdgcn_sqrtf(__builtin_fabsf(r2.x)));
                    e.y = __builtin_amdgcn_exp2f(-__builtin_amdgcn_sqrtf(__builtin_fabsf(r2.y)));
                    acc[r] += W * e;                 // pk_fma
                }
            }

            #pragma unroll
            for (int r = 0; r < 4; ++r) {
                float s = acc[r].x + acc[r].y;
                #pragma unroll
                for (int off = 32; off; off >>= 1) s += __shfl_xor(s, off);
                if (lane == 0) wpart[w][r] = s;
            }
            __syncthreads();

            // combine j-halves; write this wg's 32 duals via sc1 stores (wave 0)
            if (threadIdx.x < 32) {
                const int q = threadIdx.x >> 2;
                const int r = threadIdx.x & 3;
                float s = wpart[q][r] + wpart[q + 8][r];
                float val = -11.0f - __builtin_amdgcn_logf(s);
                __hip_atomic_store(&dw[wgrow + threadIdx.x], val,
                                   __ATOMIC_RELAXED, __HIP_MEMORY_SCOPE_AGENT);
            }

            // Epoch barrier: leader drains wave-0's dual stores, then
            // publishes epoch; wave 0 polls all 64 wg epochs (coalesced,
            // no atomic RMW). Runs on the LAST phase too (final needs it).
            const int target = it * 2 + ph + 1;
            if (threadIdx.x == 0) {
                asm volatile("s_waitcnt vmcnt(0)" ::: "memory");  // duals acked at IF
                __hip_atomic_store(&eb[wg * EPOCH_STRIDE], target,
                                   __ATOMIC_RELAXED, __HIP_MEMORY_SCOPE_AGENT);
            }
            if (w == 0) {
                int* myep = &eb[lane * EPOCH_STRIDE];   // lane l watches wg l
                for (;;) {
                    int e = __hip_atomic_load(myep, __ATOMIC_RELAXED, __HIP_MEMORY_SCOPE_AGENT);
                    if (__all(e >= target)) break;
                    __builtin_amdgcn_s_sleep(1);
                }
            }
            __syncthreads();
        }
    }

    // ---- Final fold: D, pi = exp(D+u+v) (faithful +D), cost partials ----
    {
        const int t = threadIdx.x;
        float v0 = __hip_atomic_load(&vb[t],        __ATOMIC_RELAXED, __HIP_MEMORY_SCOPE_AGENT);
        float v1 = __hip_atomic_load(&vb[t + 1024], __ATOMIC_RELAXED, __HIP_MEMORY_SCOPE_AGENT);
        ((float*)shv4)[t]        = v0;
        ((float*)shv4)[t + 1024] = v1;
    }
    __syncthreads();

    float costacc = 0.f;
    const int row0 = wgrow + 2 * w;                 // two rows per wave
    for (int rr = 0; rr < 2; ++rr) {
        const int row = row0 + rr;
        const int e = row >> 1;
        v2f xv = shx[0][e], yv = shy[0][e], zv = shz[0][e];
        const float ax = (row & 1) ? xv.y : xv.x;
        const float ay = (row & 1) ? yv.y : yv.x;
        const float az = (row & 1) ? zv.y : zv.x;
        const float u2 = __hip_atomic_load(&ub[row], __ATOMIC_RELAXED, __HIP_MEMORY_SCOPE_AGENT);
        const size_t base4 = ((size_t)b * P + row) * (P / 4);
        for (int c2 = 0; c2 < 8; ++c2) {
            const int j0 = (c2 << 8) + (lane << 2);  // 4 consecutive j
            const int tt = j0 >> 1;                  // even v2f index
            v2f X0 = shx[1][tt], X1 = shx[1][tt + 1];
            v2f Y0 = shy[1][tt], Y1 = shy[1][tt + 1];
            v2f Z0 = shz[1][tt], Z1 = shz[1][tt + 1];
            float4 vv = shv4[j0 >> 2];
            float xj[4] = {X0.x, X0.y, X1.x, X1.y};
            float yj[4] = {Y0.x, Y0.y, Y1.x, Y1.y};
            float zj[4] = {Z0.x, Z0.y, Z1.x, Z1.y};
            float4 dv, pv;
            #pragma unroll
            for (int c4 = 0; c4 < 4; ++c4) {
                float dx = ax - xj[c4];
                float dy = ay - yj[c4];
                float dz = az - zj[c4];
                float ds = __builtin_amdgcn_sqrtf(fmaf(dx, dx, fmaf(dy, dy, dz * dz))); // log2e*d
                float d = LN2 * ds;                                       // true distance
                float pi = __builtin_amdgcn_exp2f(ds + u2 + (&vv.x)[c4]); // exp(d+u+v)
                (&dv.x)[c4] = d;
                (&pv.x)[c4] = pi;
                costacc = fmaf(pi, d, costacc);
            }
            outD[base4 + (j0 >> 2)] = dv;
            outPi[base4 + (j0 >> 2)] = pv;
        }
    }
    #pragma unroll
    for (int off = 32; off; off >>= 1) costacc += __shfl_xor(costacc, off);
    if (lane == 0) wpart[w][0] = costacc;
    __syncthreads();
    if (threadIdx.x == 0) {
        float s = 0.f;
        #pragma unroll
        for (int q = 0; q < 16; ++q) s += wpart[q][0];
        wgsum[blockIdx.x] = s;
    }
}

// Deterministic per-batch cost reduction: 8 blocks x 64 threads.
__global__ __launch_bounds__(64) void sk_cost(const float* __restrict__ wgsum,
                                              float* __restrict__ cost)
{
    const int b = blockIdx.x;
    float s = wgsum[threadIdx.x * 8 + b];   // wg q of batch b is block q*8+b
    #pragma unroll
    for (int off = 32; off; off >>= 1) s += __shfl_xor(s, off);
    if (threadIdx.x == 0) cost[b] = s;
}

extern "C" void kernel_launch(void* const* d_in, const int* in_sizes, int n_in,
                              void* d_out, int out_size, void* d_ws, size_t ws_size,
                              hipStream_t stream)
{
    const float* x = (const float*)d_in[0];
    const float* y = (const float*)d_in[1];

    float* out  = (float*)d_out;
    float* cost = out;                                 // [8]
    float* pi   = out + BATCH;                         // [8*2048*2048]
    float* Dm   = pi + (size_t)BATCH * P * P;          // [8*2048*2048]

    float* u      = (float*)d_ws;                      // [16384] log2-space
    float* v      = u + BATCH * P;                     // [16384] log2-space
    float* wgsum  = v + BATCH * P;                     // [512]
    float4* xs    = (float4*)(wgsum + 512);            // [16384] float4 (16B-aligned)
    float4* ys    = xs + BATCH * P;                    // [16384] float4
    int* ep       = (int*)(ys + BATCH * P);            // [8192] epochs (padded)

    sk_prep<<<BATCH * P / 256, 256, 0, stream>>>(x, y, xs, ys, u, v, ep);

    {
        const float4* xs_c = xs;
        const float4* ys_c = ys;
        float* u_p = u;
        float* v_p = v;
        int* ep_p = ep;
        float4* pi_p = (float4*)pi;
        float4* dm_p = (float4*)Dm;
        float* wgsum_p = wgsum;
        void* args[] = { (void*)&xs_c, (void*)&ys_c, (void*)&u_p, (void*)&v_p,
                         (void*)&ep_p, (void*)&pi_p, (void*)&dm_p, (void*)&wgsum_p };
        hipError_t e = hipLaunchCooperativeKernel((const void*)sk_loop,
                                                  dim3(NWG), dim3(TPB),
                                                  args, 0, stream);
        if (e != hipSuccess) {
            // Fallback: plain launch. Grid == exact residency capacity
            // (512 wgs x 16 waves = 8192 waves = 256 CU x 32; LDS 72.6KB -> 2/CU),
            // so all wgs are co-resident by construction.
            sk_loop<<<dim3(NWG), dim3(TPB), 0, stream>>>(xs_c, ys_c, u_p, v_p,
                                                         ep_p, pi_p, dm_p, wgsum_p);
        }
    }

    sk_cost<<<BATCH, 64, 0, stream>>>(wgsum, cost);
}

// Round 12
// 17958.308 us; speedup vs baseline: 1.0201x; 1.0201x over previous
//
#include <hip/hip_runtime.h>
#include <cmath>

// Sinkhorn distance, B=8, P1=P2=2048, dim=3, EPS=1, MAX_ITER=100, THRESH=1e-9
// Outputs (flat, in return order): cost[8], pi[8*2048*2048], D[8*2048*2048]
//
// Identities / hard-won rules:
//  - Entire iteration in log2 domain; coords pre-scaled by log2(e); duals
//    log2-space; weights log2(1/2048) = -11 exactly.
//      u'_i = -11 - log2( sum_j exp2(v'_j - d'_ij) )
//  - THRESH=1e-9 < f32 ulp => reference stops only at a bitwise fixed point;
//    R8 measured none in 100 iters => run exactly 100.
//  - r2 via dot-form: r2 = |p_j|^2 + |c_i|^2 - 2 c.p (norms packed in
//    float4.w at prep); sqrt(abs(r2)) guards cancellation.
//  - Cross-wg dual exchange: 32-BIT agent-scope RELAXED atomics only
//    (64-bit atomic loads lower to RMW -> 10 GB HBM, R9).
//  - NO fences (R6: ~24us/phase of L2 maintenance).
//  - Barrier = R10's proven form: leader vmcnt-drain -> fetch_add -> ONE
//    lane spinning on ONE hot counter line. R11's padded per-wg epoch array
//    (64 lines polled by 64 lanes) generated 70 GB of coherence traffic.
//  - Final D/pi/cost folded into the persistent kernel after the last
//    barrier (268 MB of writes is the mandatory cost).

constexpr int BATCH = 8;
constexpr int P = 2048;
constexpr int MAX_ITER = 100;
constexpr int WGS_PER_BATCH = 64;            // 32 rows each
constexpr int NWG = BATCH * WGS_PER_BATCH;   // 512 blocks
constexpr int TPB = 1024;                    // 16 waves
constexpr int NPHASE = 2 * MAX_ITER;

#define LOG2E 1.44269504088896340736f
#define LN2   0.69314718055994530942f

typedef __attribute__((ext_vector_type(2))) float v2f;

static __device__ __forceinline__ v2f mkv2(float a, float b) { v2f r; r.x = a; r.y = b; return r; }

// Pack pre-scaled coords + squared norm into float4; init duals; zero counters.
__global__ __launch_bounds__(256) void sk_prep(const float* __restrict__ x,
                                               const float* __restrict__ y,
                                               float4* __restrict__ xs,
                                               float4* __restrict__ ys,
                                               float* __restrict__ u,
                                               float* __restrict__ v,
                                               int* __restrict__ cnt)
{
    int idx = blockIdx.x * 256 + threadIdx.x;   // 0 .. BATCH*P-1
    u[idx] = 0.0f;     // log2-space u0 = 0
    v[idx] = -11.0f;   // log2-space v0 = log2(1/2048)
    {
        float a = LOG2E * x[3*idx], b2 = LOG2E * x[3*idx+1], c = LOG2E * x[3*idx+2];
        xs[idx] = make_float4(a, b2, c, a*a + b2*b2 + c*c);
    }
    {
        float a = LOG2E * y[3*idx], b2 = LOG2E * y[3*idx+1], c = LOG2E * y[3*idx+2];
        ys[idx] = make_float4(a, b2, c, a*a + b2*b2 + c*c);
    }
    if (idx < BATCH * NPHASE) cnt[idx] = 0;     // re-zeroed every call
}

// Whole Sinkhorn loop + final output in one kernel.
// Block: 1024 thr = 16 waves = 8 row-quads x 2 j-halves; 32 output rows/wg.
__global__ __launch_bounds__(TPB, 8) void sk_loop(const float4* __restrict__ xs,
                                                  const float4* __restrict__ ys,
                                                  float* u,
                                                  float* v,
                                                  int* cnt,
                                                  float4* __restrict__ outPi,
                                                  float4* __restrict__ outD,
                                                  float* __restrict__ wgsum)
{
    __shared__ v2f shx[2][P/2], shy[2][P/2], shz[2][P/2], shg[2][P/2]; // 64 KiB
    __shared__ float4 shv4[P/4];                                       // 8 KiB (final)
    __shared__ float wpart[16][4];

    const int b = blockIdx.x & 7;                   // batch (XCD-local heuristic)
    const int wg = blockIdx.x >> 3;                 // 0..63 within batch
    const int wgrow = wg << 5;                      // this wg's 32-row base
    const int w = threadIdx.x >> 6;
    const int lane = threadIdx.x & 63;
    const int quad = w & 7;                         // row-quad 0..7
    const int half = w >> 3;                        // j half-range
    const int i0 = wgrow + quad * 4;
    const int tbase = half * 512 + lane;            // v2f index into LDS / duals

    const float4* xb = xs + (size_t)b * P;
    const float4* yb = ys + (size_t)b * P;
    float* ub = u + (size_t)b * P;
    float* vb = v + (size_t)b * P;
    int* bar = cnt + b * NPHASE;

    // Stage BOTH coordinate sides + norms into LDS once.
    {
        const int t = threadIdx.x;                  // 0..1023 == P/2 entries
        float4 a0 = xb[2*t], a1 = xb[2*t + 1];
        shx[0][t] = mkv2(a0.x, a1.x);
        shy[0][t] = mkv2(a0.y, a1.y);
        shz[0][t] = mkv2(a0.z, a1.z);
        shg[0][t] = mkv2(a0.w, a1.w);
        float4 c0 = yb[2*t], c1 = yb[2*t + 1];
        shx[1][t] = mkv2(c0.x, c1.x);
        shy[1][t] = mkv2(c0.y, c1.y);
        shz[1][t] = mkv2(c0.z, c1.z);
        shg[1][t] = mkv2(c0.w, c1.w);
    }
    __syncthreads();

    #pragma unroll 1
    for (int it = 0; it < MAX_ITER; ++it) {
        #pragma unroll 1
        for (int ph = 0; ph < 2; ++ph) {
            float* dr = ph ? ub : vb;               // duals being reduced over
            float* dw = ph ? vb : ub;               // duals being written
            const int side = 1 - ph;                // LDS coord side reduced over

            // Preload this wave's dual chunks from IF (32-bit sc1 loads only).
            v2f wraw[8];
            #pragma unroll
            for (int k = 0; k < 8; ++k) {
                const int t = tbase + (k << 6);
                wraw[k].x = __hip_atomic_load(&dr[2*t],     __ATOMIC_RELAXED, __HIP_MEMORY_SCOPE_AGENT);
                wraw[k].y = __hip_atomic_load(&dr[2*t + 1], __ATOMIC_RELAXED, __HIP_MEMORY_SCOPE_AGENT);
            }

            // Own output rows' coords + norms from LDS (array index == ph).
            float cx[4], cy[4], cz[4], gx[4];
            {
                const int e0 = i0 >> 1;             // v2f index of rows i0, i0+1
                v2f xa = shx[ph][e0], xbv = shx[ph][e0 + 1];
                v2f ya = shy[ph][e0], ybv = shy[ph][e0 + 1];
                v2f za = shz[ph][e0], zbv = shz[ph][e0 + 1];
                v2f ga = shg[ph][e0], gbv = shg[ph][e0 + 1];
                cx[0] = xa.x; cx[1] = xa.y; cx[2] = xbv.x; cx[3] = xbv.y;
                cy[0] = ya.x; cy[1] = ya.y; cy[2] = ybv.x; cy[3] = ybv.y;
                cz[0] = za.x; cz[1] = za.y; cz[2] = zbv.x; cz[3] = zbv.y;
                gx[0] = ga.x; gx[1] = ga.y; gx[2] = gbv.x; gx[3] = gbv.y;
            }

            v2f acc[4];
            #pragma unroll
            for (int r = 0; r < 4; ++r) acc[r] = mkv2(0.f, 0.f);

            const v2f* sx = shx[side];
            const v2f* sy = shy[side];
            const v2f* sz = shz[side];
            const v2f* sg = shg[side];

            #pragma unroll 4
            for (int k = 0; k < 8; ++k) {
                const int t = tbase + (k << 6);
                v2f X = sx[t];
                v2f Y = sy[t];
                v2f Z = sz[t];
                v2f G = sg[t];
                v2f W;                               // exp2 at use (pipelines vmcnt)
                W.x = __builtin_amdgcn_exp2f(wraw[k].x);
                W.y = __builtin_amdgcn_exp2f(wraw[k].y);
                #pragma unroll
                for (int r = 0; r < 4; ++r) {
                    v2f t1 = X * cx[r];              // dot: pk_mul + 2 pk_fma
                    t1 = Y * cy[r] + t1;
                    t1 = Z * cz[r] + t1;
                    v2f s1 = G + gx[r];              // pk_add
                    v2f r2 = t1 * (-2.0f) + s1;      // pk_fma (inline -2.0)
                    v2f e;                           // abs = free src modifier
                    e.x = __builtin_amdgcn_exp2f(-__builtin_amdgcn_sqrtf(__builtin_fabsf(r2.x)));
                    e.y = __builtin_amdgcn_exp2f(-__builtin_amdgcn_sqrtf(__builtin_fabsf(r2.y)));
                    acc[r] += W * e;                 // pk_fma
                }
            }

            #pragma unroll
            for (int r = 0; r < 4; ++r) {
                float s = acc[r].x + acc[r].y;
                #pragma unroll
                for (int off = 32; off; off >>= 1) s += __shfl_xor(s, off);
                if (lane == 0) wpart[w][r] = s;
            }
            __syncthreads();

            // combine j-halves; write this wg's 32 duals via sc1 stores (wave 0)
            if (threadIdx.x < 32) {
                const int q = threadIdx.x >> 2;
                const int r = threadIdx.x & 3;
                float s = wpart[q][r] + wpart[q + 8][r];
                float val = -11.0f - __builtin_amdgcn_logf(s);
                __hip_atomic_store(&dw[wgrow + threadIdx.x], val,
                                   __ATOMIC_RELAXED, __HIP_MEMORY_SCOPE_AGENT);
            }

            // Per-batch barrier (R10 proven): leader drains wave-0's dual
            // stores, then fetch_add + single-lane spin on ONE counter word.
            // Runs on the LAST phase too (final fold needs all duals).
            if (threadIdx.x == 0) {
                const int idx = it * 2 + ph;
                asm volatile("s_waitcnt vmcnt(0)" ::: "memory");  // duals acked at IF
                __hip_atomic_fetch_add(&bar[idx], 1, __ATOMIC_RELAXED, __HIP_MEMORY_SCOPE_AGENT);
                while (__hip_atomic_load(&bar[idx], __ATOMIC_RELAXED,
                                         __HIP_MEMORY_SCOPE_AGENT) != WGS_PER_BATCH)
                    __builtin_amdgcn_s_sleep(2);
            }
            __syncthreads();
        }
    }

    // ---- Final fold: D, pi = exp(D+u+v) (faithful +D), cost partials ----
    {
        const int t = threadIdx.x;
        float v0 = __hip_atomic_load(&vb[t],        __ATOMIC_RELAXED, __HIP_MEMORY_SCOPE_AGENT);
        float v1 = __hip_atomic_load(&vb[t + 1024], __ATOMIC_RELAXED, __HIP_MEMORY_SCOPE_AGENT);
        ((float*)shv4)[t]        = v0;
        ((float*)shv4)[t + 1024] = v1;
    }
    __syncthreads();

    float costacc = 0.f;
    const int row0 = wgrow + 2 * w;                 // two rows per wave
    for (int rr = 0; rr < 2; ++rr) {
        const int row = row0 + rr;
        const int e = row >> 1;
        v2f xv = shx[0][e], yv = shy[0][e], zv = shz[0][e];
        const float ax = (row & 1) ? xv.y : xv.x;
        const float ay = (row & 1) ? yv.y : yv.x;
        const float az = (row & 1) ? zv.y : zv.x;
        const float u2 = __hip_atomic_load(&ub[row], __ATOMIC_RELAXED, __HIP_MEMORY_SCOPE_AGENT);
        const size_t base4 = ((size_t)b * P + row) * (P / 4);
        for (int c2 = 0; c2 < 8; ++c2) {
            const int j0 = (c2 << 8) + (lane << 2);  // 4 consecutive j
            const int tt = j0 >> 1;                  // even v2f index
            v2f X0 = shx[1][tt], X1 = shx[1][tt + 1];
            v2f Y0 = shy[1][tt], Y1 = shy[1][tt + 1];
            v2f Z0 = shz[1][tt], Z1 = shz[1][tt + 1];
            float4 vv = shv4[j0 >> 2];
            float xj[4] = {X0.x, X0.y, X1.x, X1.y};
            float yj[4] = {Y0.x, Y0.y, Y1.x, Y1.y};
            float zj[4] = {Z0.x, Z0.y, Z1.x, Z1.y};
            float4 dv, pv;
            #pragma unroll
            for (int c4 = 0; c4 < 4; ++c4) {
                float dx = ax - xj[c4];
                float dy = ay - yj[c4];
                float dz = az - zj[c4];
                float ds = __builtin_amdgcn_sqrtf(fmaf(dx, dx, fmaf(dy, dy, dz * dz))); // log2e*d
                float d = LN2 * ds;                                       // true distance
                float pi = __builtin_amdgcn_exp2f(ds + u2 + (&vv.x)[c4]); // exp(d+u+v)
                (&dv.x)[c4] = d;
                (&pv.x)[c4] = pi;
                costacc = fmaf(pi, d, costacc);
            }
            outD[base4 + (j0 >> 2)] = dv;
            outPi[base4 + (j0 >> 2)] = pv;
        }
    }
    #pragma unroll
    for (int off = 32; off; off >>= 1) costacc += __shfl_xor(costacc, off);
    if (lane == 0) wpart[w][0] = costacc;
    __syncthreads();
    if (threadIdx.x == 0) {
        float s = 0.f;
        #pragma unroll
        for (int q = 0; q < 16; ++q) s += wpart[q][0];
        wgsum[blockIdx.x] = s;
    }
}

// Deterministic per-batch cost reduction: 8 blocks x 64 threads.
__global__ __launch_bounds__(64) void sk_cost(const float* __restrict__ wgsum,
                                              float* __restrict__ cost)
{
    const int b = blockIdx.x;
    float s = wgsum[threadIdx.x * 8 + b];   // wg q of batch b is block q*8+b
    #pragma unroll
    for (int off = 32; off; off >>= 1) s += __shfl_xor(s, off);
    if (threadIdx.x == 0) cost[b] = s;
}

extern "C" void kernel_launch(void* const* d_in, const int* in_sizes, int n_in,
                              void* d_out, int out_size, void* d_ws, size_t ws_size,
                              hipStream_t stream)
{
    const float* x = (const float*)d_in[0];
    const float* y = (const float*)d_in[1];

    float* out  = (float*)d_out;
    float* cost = out;                                 // [8]
    float* pi   = out + BATCH;                         // [8*2048*2048]
    float* Dm   = pi + (size_t)BATCH * P * P;          // [8*2048*2048]

    float* u      = (float*)d_ws;                      // [16384] log2-space
    float* v      = u + BATCH * P;                     // [16384] log2-space
    float* wgsum  = v + BATCH * P;                     // [512]
    float4* xs    = (float4*)(wgsum + 512);            // [16384] float4 (16B-aligned)
    float4* ys    = xs + BATCH * P;                    // [16384] float4
    int* cnt      = (int*)(ys + BATCH * P);            // [1600] barrier counters

    sk_prep<<<BATCH * P / 256, 256, 0, stream>>>(x, y, xs, ys, u, v, cnt);

    {
        const float4* xs_c = xs;
        const float4* ys_c = ys;
        float* u_p = u;
        float* v_p = v;
        int* cnt_p = cnt;
        float4* pi_p = (float4*)pi;
        float4* dm_p = (float4*)Dm;
        float* wgsum_p = wgsum;
        void* args[] = { (void*)&xs_c, (void*)&ys_c, (void*)&u_p, (void*)&v_p,
                         (void*)&cnt_p, (void*)&pi_p, (void*)&dm_p, (void*)&wgsum_p };
        hipError_t e = hipLaunchCooperativeKernel((const void*)sk_loop,
                                                  dim3(NWG), dim3(TPB),
                                                  args, 0, stream);
        if (e != hipSuccess) {
            // Fallback: plain launch. Grid == exact residency capacity
            // (512 wgs x 16 waves = 8192 waves = 256 CU x 32), so all wgs
            // are co-resident by construction.
            sk_loop<<<dim3(NWG), dim3(TPB), 0, stream>>>(xs_c, ys_c, u_p, v_p,
                                                         cnt_p, pi_p, dm_p, wgsum_p);
        }
    }

    sk_cost<<<BATCH, 64, 0, stream>>>(wgsum, cost);
}

// Round 13
// 2665.859 us; speedup vs baseline: 6.8719x; 6.7364x over previous
//
#include <hip/hip_runtime.h>
#include <cmath>

// Sinkhorn distance, B=8, P1=P2=2048, dim=3, EPS=1, MAX_ITER=100, THRESH=1e-9
// Outputs (flat, in return order): cost[8], pi[8*2048*2048], D[8*2048*2048]
//
// Identities / hard-won rules:
//  - Entire iteration in log2 domain; coords pre-scaled by log2(e); duals
//    log2-space; weights log2(1/2048) = -11 exactly.
//      u'_i = -11 - log2( sum_j exp2(v'_j - d'_ij) )
//  - THRESH=1e-9 < f32 ulp => reference stops only at a bitwise fixed point;
//    R8 measured none in 100 iters => run exactly 100.
//  - Cross-wg dual exchange: 32-BIT agent-scope RELAXED atomics only
//    (64-bit atomic loads lower to RMW -> 10 GB HBM, R9).
//  - NO fences (R6: ~24us/phase of L2 maintenance).
//  - Barrier: leader vmcnt-drain -> fetch_add -> ONE lane spinning on ONE
//    hot counter word (R11's padded per-wg epoch array: 70 GB of traffic).
//  - REGISTER BUDGET IS 64 VGPRs (launch_bounds 1024,8). R11/R12's
//    exp2-at-use + dot-form pushed peak live regs past 64 -> scratch spill
//    -> 59 GB of L2-thrashing HBM traffic, 7x slowdown. Inner loop must
//    stay in R10's proven form: W[] exp2'd at preload (wraw dies), plain
//    sub/fma distance, no extra per-row arrays.
//  - Final D/pi/cost folded into the persistent kernel after the last
//    barrier (268 MB of writes is the mandatory cost).

constexpr int BATCH = 8;
constexpr int P = 2048;
constexpr int MAX_ITER = 100;
constexpr int WGS_PER_BATCH = 64;            // 32 rows each
constexpr int NWG = BATCH * WGS_PER_BATCH;   // 512 blocks
constexpr int TPB = 1024;                    // 16 waves
constexpr int NPHASE = 2 * MAX_ITER;

#define LOG2E 1.44269504088896340736f
#define LN2   0.69314718055994530942f

typedef __attribute__((ext_vector_type(2))) float v2f;

static __device__ __forceinline__ v2f mkv2(float a, float b) { v2f r; r.x = a; r.y = b; return r; }

// Pack pre-scaled coords into float4; init duals; zero barrier counters.
__global__ __launch_bounds__(256) void sk_prep(const float* __restrict__ x,
                                               const float* __restrict__ y,
                                               float4* __restrict__ xs,
                                               float4* __restrict__ ys,
                                               float* __restrict__ u,
                                               float* __restrict__ v,
                                               int* __restrict__ cnt)
{
    int idx = blockIdx.x * 256 + threadIdx.x;   // 0 .. BATCH*P-1
    u[idx] = 0.0f;     // log2-space u0 = 0
    v[idx] = -11.0f;   // log2-space v0 = log2(1/2048)
    xs[idx] = make_float4(LOG2E * x[3*idx], LOG2E * x[3*idx+1], LOG2E * x[3*idx+2], 0.f);
    ys[idx] = make_float4(LOG2E * y[3*idx], LOG2E * y[3*idx+1], LOG2E * y[3*idx+2], 0.f);
    if (idx < BATCH * NPHASE) cnt[idx] = 0;     // re-zeroed every call
}

// Whole Sinkhorn loop + final output in one kernel.
// Block: 1024 thr = 16 waves = 8 row-quads x 2 j-halves; 32 output rows/wg.
__global__ __launch_bounds__(TPB, 8) void sk_loop(const float4* __restrict__ xs,
                                                  const float4* __restrict__ ys,
                                                  float* u,
                                                  float* v,
                                                  int* cnt,
                                                  float4* __restrict__ outPi,
                                                  float4* __restrict__ outD,
                                                  float* __restrict__ wgsum)
{
    __shared__ v2f shx[2][P/2], shy[2][P/2], shz[2][P/2];  // [side][j/2], 48 KiB
    __shared__ float4 shv4[P/4];                           // 8 KiB (final fold)
    __shared__ float wpart[16][4];

    const int b = blockIdx.x & 7;                   // batch (XCD-local heuristic)
    const int wg = blockIdx.x >> 3;                 // 0..63 within batch
    const int wgrow = wg << 5;                      // this wg's 32-row base
    const int w = threadIdx.x >> 6;
    const int lane = threadIdx.x & 63;
    const int quad = w & 7;                         // row-quad 0..7
    const int half = w >> 3;                        // j half-range
    const int i0 = wgrow + quad * 4;
    const int tbase = half * 512 + lane;            // v2f index into LDS / duals

    const float4* xb = xs + (size_t)b * P;
    const float4* yb = ys + (size_t)b * P;
    float* ub = u + (size_t)b * P;
    float* vb = v + (size_t)b * P;
    int* bar = cnt + b * NPHASE;

    // Stage BOTH coordinate sides into LDS once (read-only thereafter).
    {
        const int t = threadIdx.x;                  // 0..1023 == P/2 entries
        float4 a0 = xb[2*t], a1 = xb[2*t + 1];
        shx[0][t] = mkv2(a0.x, a1.x);
        shy[0][t] = mkv2(a0.y, a1.y);
        shz[0][t] = mkv2(a0.z, a1.z);
        float4 c0 = yb[2*t], c1 = yb[2*t + 1];
        shx[1][t] = mkv2(c0.x, c1.x);
        shy[1][t] = mkv2(c0.y, c1.y);
        shz[1][t] = mkv2(c0.z, c1.z);
    }
    __syncthreads();

    #pragma unroll 1
    for (int it = 0; it < MAX_ITER; ++it) {
        #pragma unroll 1
        for (int ph = 0; ph < 2; ++ph) {
            float* dr = ph ? ub : vb;               // duals being reduced over
            float* dw = ph ? vb : ub;               // duals being written
            const int side = 1 - ph;                // LDS coord side reduced over

            // Preload this wave's dual chunks from IF (32-bit sc1 loads only)
            // and exp2 them IMMEDIATELY (keeps wraw dead -> no spill; R12).
            v2f W[8];
            #pragma unroll
            for (int k = 0; k < 8; ++k) {
                const int t = tbase + (k << 6);
                float d0 = __hip_atomic_load(&dr[2*t],     __ATOMIC_RELAXED, __HIP_MEMORY_SCOPE_AGENT);
                float d1 = __hip_atomic_load(&dr[2*t + 1], __ATOMIC_RELAXED, __HIP_MEMORY_SCOPE_AGENT);
                W[k] = mkv2(d0, d1);
            }
            #pragma unroll
            for (int k = 0; k < 8; ++k) {
                W[k].x = __builtin_amdgcn_exp2f(W[k].x);
                W[k].y = __builtin_amdgcn_exp2f(W[k].y);
            }

            // Own output rows' coords from LDS (array index == ph).
            float cx[4], cy[4], cz[4];
            {
                const int e0 = i0 >> 1;             // v2f index of rows i0, i0+1
                v2f xa = shx[ph][e0], xbv = shx[ph][e0 + 1];
                v2f ya = shy[ph][e0], ybv = shy[ph][e0 + 1];
                v2f za = shz[ph][e0], zbv = shz[ph][e0 + 1];
                cx[0] = xa.x; cx[1] = xa.y; cx[2] = xbv.x; cx[3] = xbv.y;
                cy[0] = ya.x; cy[1] = ya.y; cy[2] = ybv.x; cy[3] = ybv.y;
                cz[0] = za.x; cz[1] = za.y; cz[2] = zbv.x; cz[3] = zbv.y;
            }

            v2f acc[4];
            #pragma unroll
            for (int r = 0; r < 4; ++r) acc[r] = mkv2(0.f, 0.f);

            const v2f* sx = shx[side];
            const v2f* sy = shy[side];
            const v2f* sz = shz[side];

            #pragma unroll 4
            for (int k = 0; k < 8; ++k) {
                const int t = tbase + (k << 6);
                v2f X = sx[t];
                v2f Y = sy[t];
                v2f Z = sz[t];
                #pragma unroll
                for (int r = 0; r < 4; ++r) {
                    v2f dx = X - cx[r];                    // v_pk_add_f32 (neg mod)
                    v2f dy = Y - cy[r];
                    v2f dz = Z - cz[r];
                    v2f r2 = dx*dx + dy*dy + dz*dz;        // v_pk_fma_f32 chain
                    v2f e;
                    e.x = __builtin_amdgcn_exp2f(-__builtin_amdgcn_sqrtf(r2.x));
                    e.y = __builtin_amdgcn_exp2f(-__builtin_amdgcn_sqrtf(r2.y));
                    acc[r] += W[k] * e;                    // v_pk_fma_f32
                }
            }

            #pragma unroll
            for (int r = 0; r < 4; ++r) {
                float s = acc[r].x + acc[r].y;
                #pragma unroll
                for (int off = 32; off; off >>= 1) s += __shfl_xor(s, off);
                if (lane == 0) wpart[w][r] = s;
            }
            __syncthreads();

            // combine j-halves; write this wg's 32 duals via sc1 stores (wave 0)
            if (threadIdx.x < 32) {
                const int q = threadIdx.x >> 2;
                const int r = threadIdx.x & 3;
                float s = wpart[q][r] + wpart[q + 8][r];
                float val = -11.0f - __builtin_amdgcn_logf(s);
                __hip_atomic_store(&dw[wgrow + threadIdx.x], val,
                                   __ATOMIC_RELAXED, __HIP_MEMORY_SCOPE_AGENT);
            }

            // Per-batch barrier: leader drains wave-0's dual stores, then
            // fetch_add + single-lane spin on ONE counter word. Runs on the
            // LAST phase too (final fold needs all duals).
            if (threadIdx.x == 0) {
                const int idx = it * 2 + ph;
                asm volatile("s_waitcnt vmcnt(0)" ::: "memory");  // duals acked at IF
                __hip_atomic_fetch_add(&bar[idx], 1, __ATOMIC_RELAXED, __HIP_MEMORY_SCOPE_AGENT);
                while (__hip_atomic_load(&bar[idx], __ATOMIC_RELAXED,
                                         __HIP_MEMORY_SCOPE_AGENT) != WGS_PER_BATCH)
                    __builtin_amdgcn_s_sleep(2);
            }
            __syncthreads();
        }
    }

    // ---- Final fold: D, pi = exp(D+u+v) (faithful +D), cost partials ----
    {
        const int t = threadIdx.x;
        float v0 = __hip_atomic_load(&vb[t],        __ATOMIC_RELAXED, __HIP_MEMORY_SCOPE_AGENT);
        float v1 = __hip_atomic_load(&vb[t + 1024], __ATOMIC_RELAXED, __HIP_MEMORY_SCOPE_AGENT);
        ((float*)shv4)[t]        = v0;
        ((float*)shv4)[t + 1024] = v1;
    }
    __syncthreads();

    float costacc = 0.f;
    const int row0 = wgrow + 2 * w;                 // two rows per wave
    for (int rr = 0; rr < 2; ++rr) {
        const int row = row0 + rr;
        const int e = row >> 1;
        v2f xv = shx[0][e], yv = shy[0][e], zv = shz[0][e];
        const float ax = (row & 1) ? xv.y : xv.x;
        const float ay = (row & 1) ? yv.y : yv.x;
        const float az = (row & 1) ? zv.y : zv.x;
        const float u2 = __hip_atomic_load(&ub[row], __ATOMIC_RELAXED, __HIP_MEMORY_SCOPE_AGENT);
        const size_t base4 = ((size_t)b * P + row) * (P / 4);
        for (int c2 = 0; c2 < 8; ++c2) {
            const int j0 = (c2 << 8) + (lane << 2);  // 4 consecutive j
            const int tt = j0 >> 1;                  // even v2f index
            v2f X0 = shx[1][tt], X1 = shx[1][tt + 1];
            v2f Y0 = shy[1][tt], Y1 = shy[1][tt + 1];
            v2f Z0 = shz[1][tt], Z1 = shz[1][tt + 1];
            float4 vv = shv4[j0 >> 2];
            float xj[4] = {X0.x, X0.y, X1.x, X1.y};
            float yj[4] = {Y0.x, Y0.y, Y1.x, Y1.y};
            float zj[4] = {Z0.x, Z0.y, Z1.x, Z1.y};
            float4 dv, pv;
            #pragma unroll
            for (int c4 = 0; c4 < 4; ++c4) {
                float dx = ax - xj[c4];
                float dy = ay - yj[c4];
                float dz = az - zj[c4];
                float ds = __builtin_amdgcn_sqrtf(fmaf(dx, dx, fmaf(dy, dy, dz * dz))); // log2e*d
                float d = LN2 * ds;                                       // true distance
                float pi = __builtin_amdgcn_exp2f(ds + u2 + (&vv.x)[c4]); // exp(d+u+v)
                (&dv.x)[c4] = d;
                (&pv.x)[c4] = pi;
                costacc = fmaf(pi, d, costacc);
            }
            outD[base4 + (j0 >> 2)] = dv;
            outPi[base4 + (j0 >> 2)] = pv;
        }
    }
    #pragma unroll
    for (int off = 32; off; off >>= 1) costacc += __shfl_xor(costacc, off);
    if (lane == 0) wpart[w][0] = costacc;
    __syncthreads();
    if (threadIdx.x == 0) {
        float s = 0.f;
        #pragma unroll
        for (int q = 0; q < 16; ++q) s += wpart[q][0];
        wgsum[blockIdx.x] = s;
    }
}

// Deterministic per-batch cost reduction: 8 blocks x 64 threads.
__global__ __launch_bounds__(64) void sk_cost(const float* __restrict__ wgsum,
                                              float* __restrict__ cost)
{
    const int b = blockIdx.x;
    float s = wgsum[threadIdx.x * 8 + b];   // wg q of batch b is block q*8+b
    #pragma unroll
    for (int off = 32; off; off >>= 1) s += __shfl_xor(s, off);
    if (threadIdx.x == 0) cost[b] = s;
}

extern "C" void kernel_launch(void* const* d_in, const int* in_sizes, int n_in,
                              void* d_out, int out_size, void* d_ws, size_t ws_size,
                              hipStream_t stream)
{
    const float* x = (const float*)d_in[0];
    const float* y = (const float*)d_in[1];

    float* out  = (float*)d_out;
    float* cost = out;                                 // [8]
    float* pi   = out + BATCH;                         // [8*2048*2048]
    float* Dm   = pi + (size_t)BATCH * P * P;          // [8*2048*2048]

    float* u      = (float*)d_ws;                      // [16384] log2-space
    float* v      = u + BATCH * P;                     // [16384] log2-space
    float* wgsum  = v + BATCH * P;                     // [512]
    float4* xs    = (float4*)(wgsum + 512);            // [16384] float4 (16B-aligned)
    float4* ys    = xs + BATCH * P;                    // [16384] float4
    int* cnt      = (int*)(ys + BATCH * P);            // [1600] barrier counters

    sk_prep<<<BATCH * P / 256, 256, 0, stream>>>(x, y, xs, ys, u, v, cnt);

    {
        const float4* xs_c = xs;
        const float4* ys_c = ys;
        float* u_p = u;
        float* v_p = v;
        int* cnt_p = cnt;
        float4* pi_p = (float4*)pi;
        float4* dm_p = (float4*)Dm;
        float* wgsum_p = wgsum;
        void* args[] = { (void*)&xs_c, (void*)&ys_c, (void*)&u_p, (void*)&v_p,
                         (void*)&cnt_p, (void*)&pi_p, (void*)&dm_p, (void*)&wgsum_p };
        hipError_t e = hipLaunchCooperativeKernel((const void*)sk_loop,
                                                  dim3(NWG), dim3(TPB),
                                                  args, 0, stream);
        if (e != hipSuccess) {
            // Fallback: plain launch. Grid == exact residency capacity
            // (512 wgs x 16 waves = 8192 waves = 256 CU x 32; LDS 56.5KB -> 2/CU),
            // so all wgs are co-resident by construction.
            sk_loop<<<dim3(NWG), dim3(TPB), 0, stream>>>(xs_c, ys_c, u_p, v_p,
                                                         cnt_p, pi_p, dm_p, wgsum_p);
        }
    }

    sk_cost<<<BATCH, 64, 0, stream>>>(wgsum, cost);
}

// Round 14
// 2427.023 us; speedup vs baseline: 7.5481x; 1.0984x over previous
//
#include <hip/hip_runtime.h>
#include <cmath>

// Sinkhorn distance, B=8, P1=P2=2048, dim=3, EPS=1, MAX_ITER=100, THRESH=1e-9
// Outputs (flat, in return order): cost[8], pi[8*2048*2048], D[8*2048*2048]
//
// Identities / hard-won rules:
//  - Entire iteration in log2 domain; coords pre-scaled by log2(e); duals
//    log2-space; weights log2(1/2048) = -11 exactly.
//      u'_i = -11 - log2( sum_j exp2(v'_j - d'_ij) )
//  - THRESH=1e-9 < f32 ulp => reference stops only at a bitwise fixed point;
//    R8 measured none in 100 iters => run exactly 100.
//  - Cross-wg dual exchange: 32-BIT agent-scope RELAXED atomics only
//    (64-bit atomic loads lower to RMW -> 10 GB HBM, R9).
//  - NO fences (R6: ~24us/phase of L2 maintenance).
//  - REGISTER BUDGET 64 VGPRs (launch_bounds 1024,8): W[] exp2'd at preload
//    so wraw dies; plain sub/fma distance (R12: dot-form + exp2-at-use
//    spilled -> 59 GB HBM, 7x slowdown).
//  - Barrier: arrival = vmcnt-drain + fetch_add on a write-only counter;
//    release = the 64th arriver stores a SEPARATE once-written flag word
//    that everyone polls (single hot clean line per batch; R11's per-wg
//    padded epoch array = 70 GB coherence traffic; R10's poll-the-counter
//    = 64 invalidation rounds per phase).
//  - Final D/pi/cost in a SEPARATE 16384-block kernel (R13: folding it into
//    the persistent kernel cost +290us — wrong shape for the 268 MB write).

constexpr int BATCH = 8;
constexpr int P = 2048;
constexpr int MAX_ITER = 100;
constexpr int WGS_PER_BATCH = 64;            // 32 rows each
constexpr int NWG = BATCH * WGS_PER_BATCH;   // 512 blocks
constexpr int TPB = 1024;                    // 16 waves
constexpr int NPHASE = 2 * MAX_ITER;

#define LOG2E 1.44269504088896340736f
#define LN2   0.69314718055994530942f

typedef __attribute__((ext_vector_type(2))) float v2f;

static __device__ __forceinline__ v2f mkv2(float a, float b) { v2f r; r.x = a; r.y = b; return r; }

// Pack pre-scaled coords into float4; init duals; zero counters + release flags.
__global__ __launch_bounds__(256) void sk_prep(const float* __restrict__ x,
                                               const float* __restrict__ y,
                                               float4* __restrict__ xs,
                                               float4* __restrict__ ys,
                                               float* __restrict__ u,
                                               float* __restrict__ v,
                                               int* __restrict__ cnt)
{
    int idx = blockIdx.x * 256 + threadIdx.x;   // 0 .. BATCH*P-1
    u[idx] = 0.0f;     // log2-space u0 = 0
    v[idx] = -11.0f;   // log2-space v0 = log2(1/2048)
    xs[idx] = make_float4(LOG2E * x[3*idx], LOG2E * x[3*idx+1], LOG2E * x[3*idx+2], 0.f);
    ys[idx] = make_float4(LOG2E * y[3*idx], LOG2E * y[3*idx+1], LOG2E * y[3*idx+2], 0.f);
    if (idx < 2 * BATCH * NPHASE) cnt[idx] = 0;   // arrivals + release flags
}

// The whole Sinkhorn loop in one kernel.
// Block: 1024 thr = 16 waves = 8 row-quads x 2 j-halves; 32 output rows/wg.
__global__ __launch_bounds__(TPB, 8) void sk_loop(const float4* __restrict__ xs,
                                                  const float4* __restrict__ ys,
                                                  float* u,
                                                  float* v,
                                                  int* cnt)
{
    __shared__ v2f shx[2][P/2], shy[2][P/2], shz[2][P/2];  // [side][j/2], 48 KiB
    __shared__ float wpart[16][4];

    const int b = blockIdx.x & 7;                   // batch (XCD-local heuristic)
    const int wg = blockIdx.x >> 3;                 // 0..63 within batch
    const int wgrow = wg << 5;                      // this wg's 32-row base
    const int w = threadIdx.x >> 6;
    const int lane = threadIdx.x & 63;
    const int quad = w & 7;                         // row-quad 0..7
    const int half = w >> 3;                        // j half-range
    const int i0 = wgrow + quad * 4;
    const int tbase = half * 512 + lane;            // v2f index into LDS / duals

    const float4* xb = xs + (size_t)b * P;
    const float4* yb = ys + (size_t)b * P;
    float* ub = u + (size_t)b * P;
    float* vb = v + (size_t)b * P;
    int* bar = cnt + b * NPHASE;                    // arrival counters (write-only)
    int* rel = cnt + BATCH * NPHASE + b * NPHASE;   // release flags (single writer)

    // Stage BOTH coordinate sides into LDS once (read-only thereafter).
    {
        const int t = threadIdx.x;                  // 0..1023 == P/2 entries
        float4 a0 = xb[2*t], a1 = xb[2*t + 1];
        shx[0][t] = mkv2(a0.x, a1.x);
        shy[0][t] = mkv2(a0.y, a1.y);
        shz[0][t] = mkv2(a0.z, a1.z);
        float4 c0 = yb[2*t], c1 = yb[2*t + 1];
        shx[1][t] = mkv2(c0.x, c1.x);
        shy[1][t] = mkv2(c0.y, c1.y);
        shz[1][t] = mkv2(c0.z, c1.z);
    }
    __syncthreads();

    #pragma unroll 1
    for (int it = 0; it < MAX_ITER; ++it) {
        #pragma unroll 1
        for (int ph = 0; ph < 2; ++ph) {
            float* dr = ph ? ub : vb;               // duals being reduced over
            float* dw = ph ? vb : ub;               // duals being written
            const int side = 1 - ph;                // LDS coord side reduced over

            // Preload this wave's dual chunks from IF (32-bit sc1 loads only)
            // and exp2 them IMMEDIATELY (keeps raw values dead -> no spill).
            v2f W[8];
            #pragma unroll
            for (int k = 0; k < 8; ++k) {
                const int t = tbase + (k << 6);
                float d0 = __hip_atomic_load(&dr[2*t],     __ATOMIC_RELAXED, __HIP_MEMORY_SCOPE_AGENT);
                float d1 = __hip_atomic_load(&dr[2*t + 1], __ATOMIC_RELAXED, __HIP_MEMORY_SCOPE_AGENT);
                W[k] = mkv2(d0, d1);
            }
            #pragma unroll
            for (int k = 0; k < 8; ++k) {
                W[k].x = __builtin_amdgcn_exp2f(W[k].x);
                W[k].y = __builtin_amdgcn_exp2f(W[k].y);
            }

            // Own output rows' coords from LDS (array index == ph).
            float cx[4], cy[4], cz[4];
            {
                const int e0 = i0 >> 1;             // v2f index of rows i0, i0+1
                v2f xa = shx[ph][e0], xbv = shx[ph][e0 + 1];
                v2f ya = shy[ph][e0], ybv = shy[ph][e0 + 1];
                v2f za = shz[ph][e0], zbv = shz[ph][e0 + 1];
                cx[0] = xa.x; cx[1] = xa.y; cx[2] = xbv.x; cx[3] = xbv.y;
                cy[0] = ya.x; cy[1] = ya.y; cy[2] = ybv.x; cy[3] = ybv.y;
                cz[0] = za.x; cz[1] = za.y; cz[2] = zbv.x; cz[3] = zbv.y;
            }

            v2f acc[4];
            #pragma unroll
            for (int r = 0; r < 4; ++r) acc[r] = mkv2(0.f, 0.f);

            const v2f* sx = shx[side];
            const v2f* sy = shy[side];
            const v2f* sz = shz[side];

            #pragma unroll 4
            for (int k = 0; k < 8; ++k) {
                const int t = tbase + (k << 6);
                v2f X = sx[t];
                v2f Y = sy[t];
                v2f Z = sz[t];
                #pragma unroll
                for (int r = 0; r < 4; ++r) {
                    v2f dx = X - cx[r];                    // v_pk_add_f32 (neg mod)
                    v2f dy = Y - cy[r];
                    v2f dz = Z - cz[r];
                    v2f r2 = dx*dx + dy*dy + dz*dz;        // v_pk_fma_f32 chain
                    v2f e;
                    e.x = __builtin_amdgcn_exp2f(-__builtin_amdgcn_sqrtf(r2.x));
                    e.y = __builtin_amdgcn_exp2f(-__builtin_amdgcn_sqrtf(r2.y));
                    acc[r] += W[k] * e;                    // v_pk_fma_f32
                }
            }

            #pragma unroll
            for (int r = 0; r < 4; ++r) {
                float s = acc[r].x + acc[r].y;
                #pragma unroll
                for (int off = 32; off; off >>= 1) s += __shfl_xor(s, off);
                if (lane == 0) wpart[w][r] = s;
            }
            __syncthreads();

            // combine j-halves; write this wg's 32 duals via sc1 stores (wave 0)
            if (threadIdx.x < 32) {
                const int q = threadIdx.x >> 2;
                const int r = threadIdx.x & 3;
                float s = wpart[q][r] + wpart[q + 8][r];
                float val = -11.0f - __builtin_amdgcn_logf(s);
                __hip_atomic_store(&dw[wgrow + threadIdx.x], val,
                                   __ATOMIC_RELAXED, __HIP_MEMORY_SCOPE_AGENT);
            }

            // Per-batch barrier, arrival/release split. Skip after last phase
            // (kernel boundary syncs before sk_final).
            if (it == MAX_ITER - 1 && ph == 1) continue;
            if (threadIdx.x == 0) {
                const int idx = it * 2 + ph;
                asm volatile("s_waitcnt vmcnt(0)" ::: "memory");  // duals acked at IF
                int old = __hip_atomic_fetch_add(&bar[idx], 1, __ATOMIC_RELAXED,
                                                 __HIP_MEMORY_SCOPE_AGENT);
                if (old == WGS_PER_BATCH - 1) {
                    // 64th arriver: its add completed (return value consumed),
                    // so all drains precede this release store.
                    __hip_atomic_store(&rel[idx], 1, __ATOMIC_RELAXED,
                                       __HIP_MEMORY_SCOPE_AGENT);
                } else {
                    while (__hip_atomic_load(&rel[idx], __ATOMIC_RELAXED,
                                             __HIP_MEMORY_SCOPE_AGENT) == 0)
                        __builtin_amdgcn_s_sleep(2);
                }
            }
            __syncthreads();
        }
    }
}

// Final: D, pi = exp(D + u + v) (faithful to reference's +D sign), rowsum of pi*D.
// One block per output row; float4 loads/stores (write-bound: 268 MB).
__global__ __launch_bounds__(256) void sk_final(const float4* __restrict__ xs,
                                                const float4* __restrict__ ys,
                                                const float* __restrict__ u,
                                                const float* __restrict__ v,
                                                float4* __restrict__ outPi,
                                                float4* __restrict__ outD,
                                                float* __restrict__ rowsum)
{
    const int row = blockIdx.x;        // b*P + i
    const int b = row >> 11;

    const float4 a = xs[row];          // scaled x_i
    const float u2 = u[row];           // log2-space u_i
    const float4* vb4 = (const float4*)(v + (size_t)b * P);
    const float4* yb = ys + (size_t)b * P;
    const size_t base4 = (size_t)row * (P / 4);

    float acc = 0.f;
    for (int t = threadIdx.x; t < P / 4; t += 256) {
        float4 dv, pv;
        float4 vv = vb4[t];
        #pragma unroll
        for (int c = 0; c < 4; ++c) {
            int j = 4 * t + c;
            float4 q = yb[j];
            float dx = a.x - q.x;
            float dy = a.y - q.y;
            float dz = a.z - q.z;
            float ds = __builtin_amdgcn_sqrtf(fmaf(dx, dx, fmaf(dy, dy, dz * dz))); // log2e*d
            float d = LN2 * ds;                                        // true distance
            float pi = __builtin_amdgcn_exp2f(ds + u2 + (&vv.x)[c]);   // exp(d+u+v)
            (&dv.x)[c] = d;
            (&pv.x)[c] = pi;
            acc = fmaf(pi, d, acc);
        }
        outD[base4 + t] = dv;
        outPi[base4 + t] = pv;
    }
    #pragma unroll
    for (int off = 32; off; off >>= 1) acc += __shfl_xor(acc, off);
    __shared__ float sred[4];
    if ((threadIdx.x & 63) == 0) sred[threadIdx.x >> 6] = acc;
    __syncthreads();
    if (threadIdx.x == 0) rowsum[row] = sred[0] + sred[1] + sred[2] + sred[3];
}

__global__ __launch_bounds__(256) void sk_cost(const float* __restrict__ rowsum,
                                               float* __restrict__ cost)
{
    const int b = blockIdx.x;
    float acc = 0.f;
    for (int i = threadIdx.x; i < P; i += 256) acc += rowsum[b * P + i];
    #pragma unroll
    for (int off = 32; off; off >>= 1) acc += __shfl_xor(acc, off);
    __shared__ float sred[4];
    if ((threadIdx.x & 63) == 0) sred[threadIdx.x >> 6] = acc;
    __syncthreads();
    if (threadIdx.x == 0) cost[b] = sred[0] + sred[1] + sred[2] + sred[3];
}

extern "C" void kernel_launch(void* const* d_in, const int* in_sizes, int n_in,
                              void* d_out, int out_size, void* d_ws, size_t ws_size,
                              hipStream_t stream)
{
    const float* x = (const float*)d_in[0];
    const float* y = (const float*)d_in[1];

    float* out  = (float*)d_out;
    float* cost = out;                                 // [8]
    float* pi   = out + BATCH;                         // [8*2048*2048]
    float* Dm   = pi + (size_t)BATCH * P * P;          // [8*2048*2048]

    float* u      = (float*)d_ws;                      // [16384] log2-space
    float* v      = u + BATCH * P;                     // [16384] log2-space
    float* rowsum = v + BATCH * P;                     // [16384]
    float4* xs    = (float4*)(rowsum + BATCH * P);     // [16384] float4
    float4* ys    = xs + BATCH * P;                    // [16384] float4
    int* cnt      = (int*)(ys + BATCH * P);            // [1600 arrivals + 1600 release]

    sk_prep<<<BATCH * P / 256, 256, 0, stream>>>(x, y, xs, ys, u, v, cnt);

    {
        const float4* xs_c = xs;
        const float4* ys_c = ys;
        float* u_p = u;
        float* v_p = v;
        int* cnt_p = cnt;
        void* args[] = { (void*)&xs_c, (void*)&ys_c, (void*)&u_p, (void*)&v_p, (void*)&cnt_p };
        hipError_t e = hipLaunchCooperativeKernel((const void*)sk_loop,
                                                  dim3(NWG), dim3(TPB),
                                                  args, 0, stream);
        if (e != hipSuccess) {
            // Fallback: plain launch. Grid == exact residency capacity
            // (512 wgs x 16 waves = 8192 waves = 256 CU x 32; LDS 48.1KB -> 2/CU),
            // so all wgs are co-resident by construction.
            sk_loop<<<dim3(NWG), dim3(TPB), 0, stream>>>(xs_c, ys_c, u_p, v_p, cnt_p);
        }
    }

    sk_final<<<BATCH * P, 256, 0, stream>>>(xs, ys, u, v,
                                            (float4*)pi, (float4*)Dm, rowsum);
    sk_cost<<<BATCH, 256, 0, stream>>>(rowsum, cost);
}